// Round 1
// 223.977 us; speedup vs baseline: 1.0085x; 1.0085x over previous
//
#include <hip/hip_runtime.h>

typedef unsigned short u16;
typedef __attribute__((ext_vector_type(8))) short short8;
typedef __attribute__((ext_vector_type(4))) float floatx4;

#define N_TOK 2048
#define DIM   2048
#define NH    32
#define NKVH  4
#define HD    64
#define KVD   256

__device__ __forceinline__ float bf2f(u16 u) {
  union { unsigned i; float f; } c; c.i = ((unsigned)u) << 16; return c.f;
}
__device__ __forceinline__ u16 f2bf(float f) {
  union { float f; unsigned i; } c; c.f = f;
  unsigned x = c.i;
  return (u16)((x + 0x7fffu + ((x >> 16) & 1u)) >> 16);
}

// async global->LDS, 16B per lane (dest = wave-uniform base + lane*16)
__device__ __forceinline__ void gload16(const u16* g, u16* l) {
#if defined(__has_builtin) && __has_builtin(__builtin_amdgcn_global_load_lds)
  __builtin_amdgcn_global_load_lds(
      (const __attribute__((address_space(1))) void*)g,
      (__attribute__((address_space(3))) void*)l, 16, 0, 0);
#else
  *(short8*)l = *(const short8*)g;
#endif
}

// ---------------------------------------------------------------------------
// Fused fp32 -> bf16 conversion of x, Wq, Wk, Wv, Wo (float4 units).
// ---------------------------------------------------------------------------
#define C_X  1048576
#define C_WQ 2097152
#define C_WK 2228224
#define C_WV 2359296
#define C_WO 3407872
__global__ __launch_bounds__(256) void cvt_all(const float* __restrict__ x,
                                               const float* __restrict__ wq,
                                               const float* __restrict__ wk,
                                               const float* __restrict__ wv,
                                               const float* __restrict__ wo,
                                               u16* __restrict__ dst) {
  int i = blockIdx.x * 256 + threadIdx.x;
  const float* src; int off;
  if      (i < C_X)  { src = x;  off = 0; }
  else if (i < C_WQ) { src = wq; off = C_X; }
  else if (i < C_WK) { src = wk; off = C_WQ; }
  else if (i < C_WV) { src = wv; off = C_WK; }
  else               { src = wo; off = C_WV; }
  float4 v = ((const float4*)src)[i - off];
  ushort4 o;
  o.x = f2bf(v.x); o.y = f2bf(v.y); o.z = f2bf(v.z); o.w = f2bf(v.w);
  ((ushort4*)dst)[i] = o;
}

// ===========================================================================
// FRAG-PACKED LAYOUTS (u16 indices; lane = q*16 + r, q=lane>>4, r=lane&15):
//  Qp: [(h*64 + sq)*4 + i*2 + c]*512 + lane*8 + j
//      = Q_rope[token = sq*32 + 16i + r][dim = h*64 + 32c + 8q + j]
//  Kp: [((kvh*32 + kt)*8) + t*2 + c]*512 + lane*8 + j
//      = K_rope[token = kt*64 + 16t + r][dim = kvh*64 + 32c + 8q + j]
//  Vp: [((kvh*32 + kt)*8) + s*4 + t]*512 + lane*8 + j
//      = V[token = kt*64 + 32s + 8q + j][dim = kvh*64 + 16t + r]
// Every attention fragment load = one contiguous 1KB wave read.
// ===========================================================================

// ---------------------------------------------------------------------------
// Fused QKV projection GEMM, 64x128 tiles, BK=32, RoPE fused, frag-packed out.
// Grid 640: tm = bid&31, tn = bid>>5 (0..19): 0..15 Q; 16..17 K; 18..19 V.
// ---------------------------------------------------------------------------
__global__ __launch_bounds__(256) void gemm_qkv(const u16* __restrict__ A,
                                                const u16* __restrict__ Wq,
                                                const u16* __restrict__ Wk,
                                                const u16* __restrict__ Wv,
                                                const float* __restrict__ cs,
                                                const float* __restrict__ sn,
                                                u16* __restrict__ Qp,
                                                u16* __restrict__ Kp,
                                                u16* __restrict__ Vp) {
  __shared__ __align__(16) u16 As[64 * 32];
  __shared__ __align__(16) u16 Bs[128 * 32];
  const int tid  = threadIdx.x;
  const int lane = tid & 63;
  const int w    = tid >> 6;
  const int r    = lane & 15, q = lane >> 4;
  const int tm = blockIdx.x & 31;
  const int tn = blockIdx.x >> 5;   // 0..19
  const int wm = w & 1, wn = w >> 1;
  const int K = DIM;

  const u16* W; int wrow0;
  if (tn < 16)      { W = Wq; wrow0 = tn * 128; }
  else if (tn < 18) { W = Wk; wrow0 = (tn - 16) * 128; }
  else              { W = Wv; wrow0 = (tn - 18) * 128; }

  const int srow = tid >> 2;          // 0..63
  const int scol = (tid & 3) * 8;
  const u16* ga = A + (size_t)(tm * 64 + srow) * K + scol;
  const u16* gb = W + (size_t)(wrow0 + srow) * K + scol;
  u16* lA = &As[tid * 8];
  u16* lB = &Bs[tid * 8];

  floatx4 acc[2][4];
#pragma unroll
  for (int a = 0; a < 2; ++a)
#pragma unroll
    for (int b = 0; b < 4; ++b) acc[a][b] = (floatx4){0.f, 0.f, 0.f, 0.f};

  for (int k0 = 0; k0 < K; k0 += 32) {
    __syncthreads();
    gload16(ga + k0, lA);
    gload16(gb + k0, lB);
    gload16(gb + k0 + (size_t)64 * K, lB + 2048);
    __syncthreads();

    short8 af[2], bf[4];
#pragma unroll
    for (int mi = 0; mi < 2; ++mi)
      af[mi] = *(const short8*)&As[(wm * 32 + mi * 16 + r) * 32 + q * 8];
#pragma unroll
    for (int nj = 0; nj < 4; ++nj)
      bf[nj] = *(const short8*)&Bs[(wn * 64 + nj * 16 + r) * 32 + q * 8];
#pragma unroll
    for (int mi = 0; mi < 2; ++mi)
#pragma unroll
      for (int nj = 0; nj < 4; ++nj)
        acc[mi][nj] = __builtin_amdgcn_mfma_f32_16x16x32_bf16(af[mi], bf[nj], acc[mi][nj], 0, 0, 0);
  }

  if (tn < 18) {
    // Q or K with fused RoPE, written frag-packed.
    const int head = (tn < 16) ? (tn * 2 + wn) : ((tn - 16) * 2 + wn);
#pragma unroll
    for (int mi = 0; mi < 2; ++mi)
#pragma unroll
      for (int g = 0; g < 4; ++g) {
        int row = tm * 64 + wm * 32 + mi * 16 + 4 * q + g;   // token
        const float* crow  = cs + (size_t)row * 64;
        const float* srow2 = sn + (size_t)row * 64;
#pragma unroll
        for (int nj = 0; nj < 2; ++nj) {
          int d = nj * 16 + r;               // head-dim 0..31 (pairs with d+32)
          float x0 = acc[mi][nj][g];
          float x1 = acc[mi][nj + 2][g];
          float o0 = x0 * crow[d]      - x1 * srow2[d];
          float o1 = x1 * crow[d + 32] + x0 * srow2[d + 32];
          int qq = d >> 3, j = d & 7;        // frag coords for both c=0 and c=1
          int lslot = (qq * 16 + (row & 15)) * 8 + j;
          if (tn < 16) {
            int sq = row >> 5, ii = (row >> 4) & 1;
            size_t base = ((size_t)(head * 64 + sq) * 4 + ii * 2) * 512 + lslot;
            Qp[base]       = f2bf(o0);       // c=0
            Qp[base + 512] = f2bf(o1);       // c=1
          } else {
            int kt = row >> 6, t = (row >> 4) & 3;
            size_t base = ((size_t)(head * 32 + kt) * 8 + t * 2) * 512 + lslot;
            Kp[base]       = f2bf(o0);
            Kp[base + 512] = f2bf(o1);
          }
        }
      }
  } else {
    // V frag-packed: uint2 = 4 consecutive tokens (j0 = (4q)&7 in {0,4})
#pragma unroll
    for (int mi = 0; mi < 2; ++mi)
#pragma unroll
      for (int nj = 0; nj < 4; ++nj) {
        int col  = (tn - 18) * 128 + wn * 64 + nj * 16 + r;   // dim 0..255
        int kvh  = col >> 6;
        int t    = (col & 63) >> 4;        // = nj
        int rr   = col & 15;               // = r
        int row0 = tm * 64 + wm * 32 + mi * 16 + 4 * q;       // token
        int kt   = row0 >> 6;
        int wk   = row0 & 63;
        int s    = wk >> 5;
        int qq   = (wk & 31) >> 3;
        int j0   = wk & 7;                 // 0 or 4
        uint2 pk;
        pk.x = (unsigned)f2bf(acc[mi][nj][0]) | ((unsigned)f2bf(acc[mi][nj][1]) << 16);
        pk.y = (unsigned)f2bf(acc[mi][nj][2]) | ((unsigned)f2bf(acc[mi][nj][3]) << 16);
        size_t idx = ((size_t)(kvh * 32 + kt) * 8 + s * 4 + t) * 512 + (qq * 16 + rr) * 8 + j0;
        *(uint2*)(Vp + idx) = pk;
      }
  }
}

// ---------------------------------------------------------------------------
// Output GEMM, 64x128 tiles, BK=32, fp32 out. Grid 512: tn=bid&15, tm=bid>>4.
// ---------------------------------------------------------------------------
__global__ __launch_bounds__(256) void gemm_out(const u16* __restrict__ A,
                                                const u16* __restrict__ W,
                                                float* __restrict__ C) {
  __shared__ __align__(16) u16 As[64 * 32];
  __shared__ __align__(16) u16 Bs[128 * 32];
  const int tid  = threadIdx.x;
  const int lane = tid & 63;
  const int w    = tid >> 6;
  const int r    = lane & 15, q = lane >> 4;
  const int tn = blockIdx.x & 15;
  const int tm = blockIdx.x >> 4;
  const int wm = w & 1, wn = w >> 1;
  const int K = DIM;

  const int srow = tid >> 2;
  const int scol = (tid & 3) * 8;
  const u16* ga = A + (size_t)(tm * 64 + srow) * K + scol;
  const u16* gb = W + (size_t)(tn * 128 + srow) * K + scol;
  u16* lA = &As[tid * 8];
  u16* lB = &Bs[tid * 8];

  floatx4 acc[2][4];
#pragma unroll
  for (int a = 0; a < 2; ++a)
#pragma unroll
    for (int b = 0; b < 4; ++b) acc[a][b] = (floatx4){0.f, 0.f, 0.f, 0.f};

  for (int k0 = 0; k0 < K; k0 += 32) {
    __syncthreads();
    gload16(ga + k0, lA);
    gload16(gb + k0, lB);
    gload16(gb + k0 + (size_t)64 * K, lB + 2048);
    __syncthreads();

    short8 af[2], bf[4];
#pragma unroll
    for (int mi = 0; mi < 2; ++mi)
      af[mi] = *(const short8*)&As[(wm * 32 + mi * 16 + r) * 32 + q * 8];
#pragma unroll
    for (int nj = 0; nj < 4; ++nj)
      bf[nj] = *(const short8*)&Bs[(wn * 64 + nj * 16 + r) * 32 + q * 8];
#pragma unroll
    for (int mi = 0; mi < 2; ++mi)
#pragma unroll
      for (int nj = 0; nj < 4; ++nj)
        acc[mi][nj] = __builtin_amdgcn_mfma_f32_16x16x32_bf16(af[mi], bf[nj], acc[mi][nj], 0, 0, 0);
  }

#pragma unroll
  for (int mi = 0; mi < 2; ++mi)
#pragma unroll
    for (int g = 0; g < 4; ++g) {
      int row = tm * 64 + wm * 32 + mi * 16 + 4 * q + g;
#pragma unroll
      for (int nj = 0; nj < 4; ++nj)
        C[(size_t)row * DIM + tn * 128 + wn * 64 + nj * 16 + r] = acc[mi][nj][g];
    }
}

// ---------------------------------------------------------------------------
// 2-wave key-split barrier-free-inner-loop MFMA flash attention.
// Wave w handles key tiles kt ≡ w (mod 2). Plain-exp softmax (no running max)
// means partials combine exactly: O = O0+O1, lsum = lsum0+lsum1 — one LDS
// reduction per block. Doubles resident waves/SIMD (2 -> 4) and halves the
// longest wave's serial tile count (31 -> 16).
// ---------------------------------------------------------------------------
__global__ __launch_bounds__(128, 2) void attn_mfma(const u16* __restrict__ Qp,
                                                    const u16* __restrict__ Kp,
                                                    const u16* __restrict__ Vp,
                                                    u16* __restrict__ Yb) {
  __shared__ __align__(16) u16 Pl[2][32][72];
  __shared__ float Ocmb[32][66];   // [reg 0..31][lane], stride 66 -> 2-way banks
  __shared__ float Lcmb[2][64];
  const int tid  = threadIdx.x;
  const int lane = tid & 63;
  const int w    = tid >> 6;       // 0 or 1: key-parity
  const int r    = lane & 15;
  const int q    = lane >> 4;
  const int bx   = blockIdx.x;
  const int qt   = 15 - (bx >> 2);
  const int sub  = 3 - (bx & 3);
  const int h    = blockIdx.y;
  const int kvh  = h >> 3;
  const int baseq = qt * 128 + sub * 32;
  const int sq   = baseq >> 5;
  const int ktmax = (baseq + 31) >> 6;   // inclusive

  // Q frags: one 1KB wave read each
  short8 qf[2][2];
#pragma unroll
  for (int i = 0; i < 2; ++i)
#pragma unroll
    for (int c = 0; c < 2; ++c)
      qf[i][c] = *(const short8*)(Qp + ((size_t)(h * 64 + sq) * 4 + i * 2 + c) * 512 + lane * 8);

  floatx4 O[2][4];
  float lsum[2];
#pragma unroll
  for (int i = 0; i < 2; ++i) {
    lsum[i] = 0.f;
#pragma unroll
    for (int t = 0; t < 4; ++t) O[i][t] = (floatx4){0.f, 0.f, 0.f, 0.f};
  }

  const u16* Kbase = Kp + (size_t)(kvh * 32) * 8 * 512;
  const u16* Vbase = Vp + (size_t)(kvh * 32) * 8 * 512;

  auto loadK = [&](int kt, short8 (&kf)[4][2]) {
    const u16* kb = Kbase + (size_t)kt * 8 * 512 + lane * 8;
#pragma unroll
    for (int t = 0; t < 4; ++t) {
      kf[t][0] = *(const short8*)(kb + (t * 2 + 0) * 512);
      kf[t][1] = *(const short8*)(kb + (t * 2 + 1) * 512);
    }
  };

  auto body = [&](int kt, short8 (&kc)[4][2], short8 (&kn)[4][2]) {
    // V for CURRENT tile: issued first, consumed at the bottom
    short8 vb[2][4];
    {
      const u16* vbp = Vbase + (size_t)kt * 8 * 512 + lane * 8;
#pragma unroll
      for (int s = 0; s < 2; ++s)
#pragma unroll
        for (int t = 0; t < 4; ++t)
          vb[s][t] = *(const short8*)(vbp + (s * 4 + t) * 512);
    }

    // K for tile kt+2 (this wave's next): issued now, consumed next body
    loadK(kt + 2 <= ktmax ? kt + 2 : ktmax, kn);

    // ---- S^T = K Q^T (kc already resident) ----
    floatx4 ST[2][4];
#pragma unroll
    for (int i = 0; i < 2; ++i)
#pragma unroll
      for (int t = 0; t < 4; ++t) ST[i][t] = (floatx4){0.f, 0.f, 0.f, 0.f};
#pragma unroll
    for (int t = 0; t < 4; ++t)
#pragma unroll
      for (int i = 0; i < 2; ++i) {
        ST[i][t] = __builtin_amdgcn_mfma_f32_16x16x32_bf16(kc[t][0], qf[i][0], ST[i][t], 0, 0, 0);
        ST[i][t] = __builtin_amdgcn_mfma_f32_16x16x32_bf16(kc[t][1], qf[i][1], ST[i][t], 0, 0, 0);
      }

    // ---- causal mask (only the last tile can clip) ----
    if (kt == ktmax) {
#pragma unroll
      for (int i = 0; i < 2; ++i) {
        int qrow = baseq + 16 * i + r;
#pragma unroll
        for (int t = 0; t < 4; ++t) {
          int key = kt * 64 + 16 * t + 4 * q;
#pragma unroll
          for (int g = 0; g < 4; ++g)
            if (key + g > qrow) ST[i][t][g] = -1e30f;
        }
      }
    }

    // ---- p = exp(scale*s); per-lane partial row-sums; packed P -> LDS ----
#pragma unroll
    for (int i = 0; i < 2; ++i)
#pragma unroll
      for (int t = 0; t < 4; ++t) {
        float p0 = __expf(0.125f * ST[i][t][0]);
        float p1 = __expf(0.125f * ST[i][t][1]);
        float p2 = __expf(0.125f * ST[i][t][2]);
        float p3 = __expf(0.125f * ST[i][t][3]);
        lsum[i] += (p0 + p1) + (p2 + p3);
        uint2 pk;
        pk.x = (unsigned)f2bf(p0) | ((unsigned)f2bf(p1) << 16);
        pk.y = (unsigned)f2bf(p2) | ((unsigned)f2bf(p3) << 16);
        *(uint2*)&Pl[w][16 * i + r][16 * t + 4 * q] = pk;   // ds_write_b64
      }

    // ---- O += P V ----
#pragma unroll
    for (int s = 0; s < 2; ++s)
#pragma unroll
      for (int i = 0; i < 2; ++i) {
        short8 pa = *(const short8*)&Pl[w][16 * i + r][32 * s + 8 * q];
#pragma unroll
        for (int t = 0; t < 4; ++t)
          O[i][t] = __builtin_amdgcn_mfma_f32_16x16x32_bf16(pa, vb[s][t], O[i][t], 0, 0, 0);
      }
  };

  // Per-wave key loop: kt = w, w+2, w+4, ... <= ktmax, with K double-buffer.
  short8 kA[4][2], kB[4][2];
  const int kt0 = w;
  if (kt0 <= ktmax) {
    loadK(kt0, kA);
    for (int kt = kt0; kt <= ktmax; kt += 4) {
      body(kt, kA, kB);
      if (kt + 2 <= ktmax) body(kt + 2, kB, kA);
    }
  }

  // ---- cross-wave combine: O = O0 + O1, lsum = lsum0 + lsum1 ----
  if (w == 1) {
#pragma unroll
    for (int i = 0; i < 2; ++i) {
#pragma unroll
      for (int t = 0; t < 4; ++t)
#pragma unroll
        for (int g = 0; g < 4; ++g)
          Ocmb[(i * 4 + t) * 4 + g][lane] = O[i][t][g];
      Lcmb[i][lane] = lsum[i];
    }
  }
  __syncthreads();
  if (w == 1) return;
#pragma unroll
  for (int i = 0; i < 2; ++i) {
#pragma unroll
    for (int t = 0; t < 4; ++t)
#pragma unroll
      for (int g = 0; g < 4; ++g)
        O[i][t][g] += Ocmb[(i * 4 + t) * 4 + g][lane];
    lsum[i] += Lcmb[i][lane];
  }

  // ---- reduce row-sums over q-groups, normalize, store ----
#pragma unroll
  for (int i = 0; i < 2; ++i) {
    lsum[i] += __shfl_xor(lsum[i], 16);
    lsum[i] += __shfl_xor(lsum[i], 32);   // lane(q,r) holds sum for row r
  }

#pragma unroll
  for (int i = 0; i < 2; ++i) {
    float inv[4];
#pragma unroll
    for (int g = 0; g < 4; ++g)
      inv[g] = 1.f / __shfl(lsum[i], 4 * q + g);
#pragma unroll
    for (int g = 0; g < 4; ++g) {
      u16* yp = Yb + (size_t)(baseq + 16 * i + 4 * q + g) * DIM + h * 64 + r;
      yp[0]  = f2bf(O[i][0][g] * inv[g]);
      yp[16] = f2bf(O[i][1][g] * inv[g]);
      yp[32] = f2bf(O[i][2][g] * inv[g]);
      yp[48] = f2bf(O[i][3][g] * inv[g]);
    }
  }
}

// ---------------------------------------------------------------------------
extern "C" void kernel_launch(void* const* d_in, const int* in_sizes, int n_in,
                              void* d_out, int out_size, void* d_ws, size_t ws_size,
                              hipStream_t stream) {
  const float* x  = (const float*)d_in[0];
  const float* Wq = (const float*)d_in[1];
  const float* Wk = (const float*)d_in[2];
  const float* Wv = (const float*)d_in[3];
  const float* Wo = (const float*)d_in[4];
  const float* cs = (const float*)d_in[5];
  const float* sn = (const float*)d_in[6];

  u16* ws  = (u16*)d_ws;
  u16* xb  = ws;                            // order must match cvt_all segments
  u16* Wqb = xb  + (size_t)N_TOK * DIM;
  u16* Wkb = Wqb + (size_t)DIM * DIM;
  u16* Wvb = Wkb + (size_t)KVD * DIM;
  u16* Wob = Wvb + (size_t)KVD * DIM;
  u16* Qp  = Wob + (size_t)DIM * DIM;       // frag-packed Q (8MB)
  u16* Kp  = Qp  + (size_t)N_TOK * DIM;     // frag-packed K (1MB)
  u16* Vp  = Kp  + (size_t)N_TOK * KVD;     // frag-packed V (1MB)
  u16* Yb  = Vp  + (size_t)N_TOK * KVD;

  // fp32 -> bf16 (x + 4 weights); cos/sin consumed as fp32 by gemm_qkv
  cvt_all<<<dim3(13312), 256, 0, stream>>>(x, Wq, Wk, Wv, Wo, ws);

  // Fused QKV projection + RoPE, frag-packed outputs
  gemm_qkv<<<dim3(640), 256, 0, stream>>>(xb, Wqb, Wkb, Wvb, cs, sn, Qp, Kp, Vp);

  // 2-wave key-split pipelined attention on frag-packed tensors
  attn_mfma<<<dim3(64, 32), 128, 0, stream>>>(Qp, Kp, Vp, Yb);

  // Output projection (fp32 straight to d_out)
  gemm_out<<<dim3(512), 256, 0, stream>>>(Yb, Wob, (float*)d_out);
}

// Round 3
// 207.398 us; speedup vs baseline: 1.0891x; 1.0799x over previous
//
#include <hip/hip_runtime.h>

typedef unsigned short u16;
typedef __attribute__((ext_vector_type(8))) short short8;
typedef __attribute__((ext_vector_type(4))) float floatx4;

#define N_TOK 2048
#define DIM   2048
#define NH    32
#define NKVH  4
#define HD    64
#define KVD   256

__device__ __forceinline__ float bf2f(u16 u) {
  union { unsigned i; float f; } c; c.i = ((unsigned)u) << 16; return c.f;
}
__device__ __forceinline__ u16 f2bf(float f) {
  union { float f; unsigned i; } c; c.f = f;
  unsigned x = c.i;
  return (u16)((x + 0x7fffu + ((x >> 16) & 1u)) >> 16);
}

// async global->LDS, 16B per lane (dest = wave-uniform base + lane*16)
__device__ __forceinline__ void gload16(const u16* g, u16* l) {
#if defined(__has_builtin) && __has_builtin(__builtin_amdgcn_global_load_lds)
  __builtin_amdgcn_global_load_lds(
      (const __attribute__((address_space(1))) void*)g,
      (__attribute__((address_space(3))) void*)l, 16, 0, 0);
#else
  *(short8*)l = *(const short8*)g;
#endif
}

// ---------------------------------------------------------------------------
// Fused fp32 -> bf16 conversion of x, Wq, Wk, Wv, Wo (float4 units).
// ---------------------------------------------------------------------------
#define C_X  1048576
#define C_WQ 2097152
#define C_WK 2228224
#define C_WV 2359296
#define C_WO 3407872
__global__ __launch_bounds__(256) void cvt_all(const float* __restrict__ x,
                                               const float* __restrict__ wq,
                                               const float* __restrict__ wk,
                                               const float* __restrict__ wv,
                                               const float* __restrict__ wo,
                                               u16* __restrict__ dst) {
  int i = blockIdx.x * 256 + threadIdx.x;
  const float* src; int off;
  if      (i < C_X)  { src = x;  off = 0; }
  else if (i < C_WQ) { src = wq; off = C_X; }
  else if (i < C_WK) { src = wk; off = C_WQ; }
  else if (i < C_WV) { src = wv; off = C_WK; }
  else               { src = wo; off = C_WV; }
  float4 v = ((const float4*)src)[i - off];
  ushort4 o;
  o.x = f2bf(v.x); o.y = f2bf(v.y); o.z = f2bf(v.z); o.w = f2bf(v.w);
  ((ushort4*)dst)[i] = o;
}

// ===========================================================================
// FRAG-PACKED LAYOUTS (u16 indices; lane = q*16 + r, q=lane>>4, r=lane&15):
//  Qp: [(h*64 + sq)*4 + i*2 + c]*512 + lane*8 + j
//  Kp: [((kvh*32 + kt)*8) + t*2 + c]*512 + lane*8 + j
//  Vp: [((kvh*32 + kt)*8) + s*4 + t]*512 + lane*8 + j
// Every attention fragment load = one contiguous 1KB wave read.
// ===========================================================================

// ---------------------------------------------------------------------------
// Fused QKV projection GEMM, 64x128 tiles, BK=32, RoPE fused, frag-packed out.
// ---------------------------------------------------------------------------
__global__ __launch_bounds__(256) void gemm_qkv(const u16* __restrict__ A,
                                                const u16* __restrict__ Wq,
                                                const u16* __restrict__ Wk,
                                                const u16* __restrict__ Wv,
                                                const float* __restrict__ cs,
                                                const float* __restrict__ sn,
                                                u16* __restrict__ Qp,
                                                u16* __restrict__ Kp,
                                                u16* __restrict__ Vp) {
  __shared__ __align__(16) u16 As[64 * 32];
  __shared__ __align__(16) u16 Bs[128 * 32];
  const int tid  = threadIdx.x;
  const int lane = tid & 63;
  const int w    = tid >> 6;
  const int r    = lane & 15, q = lane >> 4;
  const int tm = blockIdx.x & 31;
  const int tn = blockIdx.x >> 5;   // 0..19
  const int wm = w & 1, wn = w >> 1;
  const int K = DIM;

  const u16* W; int wrow0;
  if (tn < 16)      { W = Wq; wrow0 = tn * 128; }
  else if (tn < 18) { W = Wk; wrow0 = (tn - 16) * 128; }
  else              { W = Wv; wrow0 = (tn - 18) * 128; }

  const int srow = tid >> 2;          // 0..63
  const int scol = (tid & 3) * 8;
  const u16* ga = A + (size_t)(tm * 64 + srow) * K + scol;
  const u16* gb = W + (size_t)(wrow0 + srow) * K + scol;
  u16* lA = &As[tid * 8];
  u16* lB = &Bs[tid * 8];

  floatx4 acc[2][4];
#pragma unroll
  for (int a = 0; a < 2; ++a)
#pragma unroll
    for (int b = 0; b < 4; ++b) acc[a][b] = (floatx4){0.f, 0.f, 0.f, 0.f};

  for (int k0 = 0; k0 < K; k0 += 32) {
    __syncthreads();
    gload16(ga + k0, lA);
    gload16(gb + k0, lB);
    gload16(gb + k0 + (size_t)64 * K, lB + 2048);
    __syncthreads();

    short8 af[2], bf[4];
#pragma unroll
    for (int mi = 0; mi < 2; ++mi)
      af[mi] = *(const short8*)&As[(wm * 32 + mi * 16 + r) * 32 + q * 8];
#pragma unroll
    for (int nj = 0; nj < 4; ++nj)
      bf[nj] = *(const short8*)&Bs[(wn * 64 + nj * 16 + r) * 32 + q * 8];
#pragma unroll
    for (int mi = 0; mi < 2; ++mi)
#pragma unroll
      for (int nj = 0; nj < 4; ++nj)
        acc[mi][nj] = __builtin_amdgcn_mfma_f32_16x16x32_bf16(af[mi], bf[nj], acc[mi][nj], 0, 0, 0);
  }

  if (tn < 18) {
    const int head = (tn < 16) ? (tn * 2 + wn) : ((tn - 16) * 2 + wn);
#pragma unroll
    for (int mi = 0; mi < 2; ++mi)
#pragma unroll
      for (int g = 0; g < 4; ++g) {
        int row = tm * 64 + wm * 32 + mi * 16 + 4 * q + g;   // token
        const float* crow  = cs + (size_t)row * 64;
        const float* srow2 = sn + (size_t)row * 64;
#pragma unroll
        for (int nj = 0; nj < 2; ++nj) {
          int d = nj * 16 + r;               // head-dim 0..31 (pairs with d+32)
          float x0 = acc[mi][nj][g];
          float x1 = acc[mi][nj + 2][g];
          float o0 = x0 * crow[d]      - x1 * srow2[d];
          float o1 = x1 * crow[d + 32] + x0 * srow2[d + 32];
          int qq = d >> 3, j = d & 7;
          int lslot = (qq * 16 + (row & 15)) * 8 + j;
          if (tn < 16) {
            int sq = row >> 5, ii = (row >> 4) & 1;
            size_t base = ((size_t)(head * 64 + sq) * 4 + ii * 2) * 512 + lslot;
            Qp[base]       = f2bf(o0);
            Qp[base + 512] = f2bf(o1);
          } else {
            int kt = row >> 6, t = (row >> 4) & 3;
            size_t base = ((size_t)(head * 32 + kt) * 8 + t * 2) * 512 + lslot;
            Kp[base]       = f2bf(o0);
            Kp[base + 512] = f2bf(o1);
          }
        }
      }
  } else {
#pragma unroll
    for (int mi = 0; mi < 2; ++mi)
#pragma unroll
      for (int nj = 0; nj < 4; ++nj) {
        int col  = (tn - 18) * 128 + wn * 64 + nj * 16 + r;   // dim 0..255
        int kvh  = col >> 6;
        int t    = (col & 63) >> 4;
        int rr   = col & 15;
        int row0 = tm * 64 + wm * 32 + mi * 16 + 4 * q;       // token
        int kt   = row0 >> 6;
        int wk   = row0 & 63;
        int s    = wk >> 5;
        int qq   = (wk & 31) >> 3;
        int j0   = wk & 7;
        uint2 pk;
        pk.x = (unsigned)f2bf(acc[mi][nj][0]) | ((unsigned)f2bf(acc[mi][nj][1]) << 16);
        pk.y = (unsigned)f2bf(acc[mi][nj][2]) | ((unsigned)f2bf(acc[mi][nj][3]) << 16);
        size_t idx = ((size_t)(kvh * 32 + kt) * 8 + s * 4 + t) * 512 + (qq * 16 + rr) * 8 + j0;
        *(uint2*)(Vp + idx) = pk;
      }
  }
}

// ---------------------------------------------------------------------------
// Output GEMM, 64x128 tiles, BK=32, fp32 out.
// ---------------------------------------------------------------------------
__global__ __launch_bounds__(256) void gemm_out(const u16* __restrict__ A,
                                                const u16* __restrict__ W,
                                                float* __restrict__ C) {
  __shared__ __align__(16) u16 As[64 * 32];
  __shared__ __align__(16) u16 Bs[128 * 32];
  const int tid  = threadIdx.x;
  const int lane = tid & 63;
  const int w    = tid >> 6;
  const int r    = lane & 15, q = lane >> 4;
  const int tn = blockIdx.x & 15;
  const int tm = blockIdx.x >> 4;
  const int wm = w & 1, wn = w >> 1;
  const int K = DIM;

  const int srow = tid >> 2;
  const int scol = (tid & 3) * 8;
  const u16* ga = A + (size_t)(tm * 64 + srow) * K + scol;
  const u16* gb = W + (size_t)(tn * 128 + srow) * K + scol;
  u16* lA = &As[tid * 8];
  u16* lB = &Bs[tid * 8];

  floatx4 acc[2][4];
#pragma unroll
  for (int a = 0; a < 2; ++a)
#pragma unroll
    for (int b = 0; b < 4; ++b) acc[a][b] = (floatx4){0.f, 0.f, 0.f, 0.f};

  for (int k0 = 0; k0 < K; k0 += 32) {
    __syncthreads();
    gload16(ga + k0, lA);
    gload16(gb + k0, lB);
    gload16(gb + k0 + (size_t)64 * K, lB + 2048);
    __syncthreads();

    short8 af[2], bf[4];
#pragma unroll
    for (int mi = 0; mi < 2; ++mi)
      af[mi] = *(const short8*)&As[(wm * 32 + mi * 16 + r) * 32 + q * 8];
#pragma unroll
    for (int nj = 0; nj < 4; ++nj)
      bf[nj] = *(const short8*)&Bs[(wn * 64 + nj * 16 + r) * 32 + q * 8];
#pragma unroll
    for (int mi = 0; mi < 2; ++mi)
#pragma unroll
      for (int nj = 0; nj < 4; ++nj)
        acc[mi][nj] = __builtin_amdgcn_mfma_f32_16x16x32_bf16(af[mi], bf[nj], acc[mi][nj], 0, 0, 0);
  }

#pragma unroll
  for (int mi = 0; mi < 2; ++mi)
#pragma unroll
    for (int g = 0; g < 4; ++g) {
      int row = tm * 64 + wm * 32 + mi * 16 + 4 * q + g;
#pragma unroll
      for (int nj = 0; nj < 4; ++nj)
        C[(size_t)row * DIM + tn * 128 + wn * 64 + nj * 16 + r] = acc[mi][nj][g];
    }
}

// ---------------------------------------------------------------------------
// Balanced pair-scheduled MFMA flash attention.
// Block p handles q-blocks {63-p, p}: tiles(63-p)+tiles(p) == 33 for ALL p,
// so every block (and every CU, under ANY dispatcher mapping) carries equal
// work. The 2 waves split the combined 33-tile list by parity (17/16 each).
// Softmax arithmetic is the R1-proven form (__expf + manual f2bf packing).
// ---------------------------------------------------------------------------
__global__ __launch_bounds__(128, 2) void attn_mfma(const u16* __restrict__ Qp,
                                                    const u16* __restrict__ Kp,
                                                    const u16* __restrict__ Vp,
                                                    u16* __restrict__ Yb) {
  __shared__ __align__(16) u16 Pl[2][32][72];
  __shared__ float OcA[32][66];   // wave1's partial for q-block A
  __shared__ float OcB[32][66];   // wave0's partial for q-block B
  __shared__ float LcA[2][64], LcB[2][64];
  const int tid  = threadIdx.x;
  const int lane = tid & 63;
  const int w    = tid >> 6;       // 0 or 1
  const int r    = lane & 15;
  const int q    = lane >> 4;
  const int p    = blockIdx.x;     // 0..31 pair index
  const int h    = blockIdx.y;
  const int kvh  = h >> 3;
  const int jA   = 63 - p;         // heavy q-block
  const int jB   = p;              // light q-block
  const int baseqA = jA * 32, baseqB = jB * 32;
  const int tA = (jA >> 1) + 1, tB = (jB >> 1) + 1;   // tile counts
  const int ktmaxA = tA - 1, ktmaxB = tB - 1;

  // Q frags: one 1KB wave read each (sq == j for 32-row q-blocks)
  short8 qfA[2][2], qfB[2][2];
#pragma unroll
  for (int i = 0; i < 2; ++i)
#pragma unroll
    for (int c = 0; c < 2; ++c) {
      qfA[i][c] = *(const short8*)(Qp + ((size_t)(h * 64 + jA) * 4 + i * 2 + c) * 512 + lane * 8);
      qfB[i][c] = *(const short8*)(Qp + ((size_t)(h * 64 + jB) * 4 + i * 2 + c) * 512 + lane * 8);
    }

  floatx4 OA[2][4], OB[2][4];
  float lsumA[2], lsumB[2];
#pragma unroll
  for (int i = 0; i < 2; ++i) {
    lsumA[i] = 0.f; lsumB[i] = 0.f;
#pragma unroll
    for (int t = 0; t < 4; ++t) {
      OA[i][t] = (floatx4){0.f, 0.f, 0.f, 0.f};
      OB[i][t] = (floatx4){0.f, 0.f, 0.f, 0.f};
    }
  }

  const u16* Kbase = Kp + (size_t)(kvh * 32) * 8 * 512;
  const u16* Vbase = Vp + (size_t)(kvh * 32) * 8 * 512;

  auto loadK = [&](int kt, short8 (&kf)[4][2]) {
    const u16* kb = Kbase + (size_t)kt * 8 * 512 + lane * 8;
#pragma unroll
    for (int t = 0; t < 4; ++t) {
      kf[t][0] = *(const short8*)(kb + (t * 2 + 0) * 512);
      kf[t][1] = *(const short8*)(kb + (t * 2 + 1) * 512);
    }
  };

  auto body = [&](int kt, int ktmax, int baseq,
                  short8 (&qf)[2][2], floatx4 (&O)[2][4], float (&lsum)[2],
                  short8 (&kc)[4][2], short8 (&kn)[4][2]) {
    // V for CURRENT tile: issued first, consumed at the bottom
    short8 vb[2][4];
    {
      const u16* vbp = Vbase + (size_t)kt * 8 * 512 + lane * 8;
#pragma unroll
      for (int s = 0; s < 2; ++s)
#pragma unroll
        for (int t = 0; t < 4; ++t)
          vb[s][t] = *(const short8*)(vbp + (s * 4 + t) * 512);
    }

    // K for this wave's next tile (kt+2), clamped, branchless
    loadK(kt + 2 <= ktmax ? kt + 2 : ktmax, kn);

    // ---- S^T = K Q^T ----
    floatx4 ST[2][4];
#pragma unroll
    for (int i = 0; i < 2; ++i)
#pragma unroll
      for (int t = 0; t < 4; ++t) ST[i][t] = (floatx4){0.f, 0.f, 0.f, 0.f};
#pragma unroll
    for (int t = 0; t < 4; ++t)
#pragma unroll
      for (int i = 0; i < 2; ++i) {
        ST[i][t] = __builtin_amdgcn_mfma_f32_16x16x32_bf16(kc[t][0], qf[i][0], ST[i][t], 0, 0, 0);
        ST[i][t] = __builtin_amdgcn_mfma_f32_16x16x32_bf16(kc[t][1], qf[i][1], ST[i][t], 0, 0, 0);
      }

    // ---- causal mask (only the last tile of this q-block can clip) ----
    if (kt == ktmax) {
#pragma unroll
      for (int i = 0; i < 2; ++i) {
        int qrow = baseq + 16 * i + r;
#pragma unroll
        for (int t = 0; t < 4; ++t) {
          int key = kt * 64 + 16 * t + 4 * q;
#pragma unroll
          for (int g = 0; g < 4; ++g)
            if (key + g > qrow) ST[i][t][g] = -1e30f;
        }
      }
    }

    // ---- p = exp(scale*s); partial row-sums; packed P -> LDS ----
#pragma unroll
    for (int i = 0; i < 2; ++i)
#pragma unroll
      for (int t = 0; t < 4; ++t) {
        float p0 = __expf(0.125f * ST[i][t][0]);
        float p1 = __expf(0.125f * ST[i][t][1]);
        float p2 = __expf(0.125f * ST[i][t][2]);
        float p3 = __expf(0.125f * ST[i][t][3]);
        lsum[i] += (p0 + p1) + (p2 + p3);
        uint2 pk;
        pk.x = (unsigned)f2bf(p0) | ((unsigned)f2bf(p1) << 16);
        pk.y = (unsigned)f2bf(p2) | ((unsigned)f2bf(p3) << 16);
        *(uint2*)&Pl[w][16 * i + r][16 * t + 4 * q] = pk;   // ds_write_b64
      }

    // ---- O += P V ----
#pragma unroll
    for (int s = 0; s < 2; ++s)
#pragma unroll
      for (int i = 0; i < 2; ++i) {
        short8 pa = *(const short8*)&Pl[w][16 * i + r][32 * s + 8 * q];
#pragma unroll
        for (int t = 0; t < 4; ++t)
          O[i][t] = __builtin_amdgcn_mfma_f32_16x16x32_bf16(pa, vb[s][t], O[i][t], 0, 0, 0);
      }
  };

  auto runloop = [&](int start, int ktmax, int baseq,
                     short8 (&qf)[2][2], floatx4 (&O)[2][4], float (&lsum)[2]) {
    if (start > ktmax) return;
    short8 kA[4][2], kB[4][2];
    loadK(start, kA);
    for (int kt = start; kt <= ktmax; kt += 4) {
      body(kt, ktmax, baseq, qf, O, lsum, kA, kB);
      if (kt + 2 <= ktmax) body(kt + 2, ktmax, baseq, qf, O, lsum, kB, kA);
    }
  };

  // Wave w takes items [w::2] of the combined list [A-tiles..., B-tiles...]
  runloop(w, ktmaxA, baseqA, qfA, OA, lsumA);
  const int sB = (w + tA) & 1;   // parity continuation into the B-tiles
  runloop(sB, ktmaxB, baseqB, qfB, OB, lsumB);

  // ---- cross-wave combine: each wave publishes its partial of the OTHER
  //      wave's output block, then finalizes its own. ----
  if (w == 1) {
#pragma unroll
    for (int i = 0; i < 2; ++i) {
#pragma unroll
      for (int t = 0; t < 4; ++t)
#pragma unroll
        for (int g = 0; g < 4; ++g)
          OcA[(i * 4 + t) * 4 + g][lane] = OA[i][t][g];
      LcA[i][lane] = lsumA[i];
    }
  } else {
#pragma unroll
    for (int i = 0; i < 2; ++i) {
#pragma unroll
      for (int t = 0; t < 4; ++t)
#pragma unroll
        for (int g = 0; g < 4; ++g)
          OcB[(i * 4 + t) * 4 + g][lane] = OB[i][t][g];
      LcB[i][lane] = lsumB[i];
    }
  }
  __syncthreads();

  auto finalize = [&](int baseq, floatx4 (&O)[2][4], float (&lsum)[2]) {
#pragma unroll
    for (int i = 0; i < 2; ++i) {
      lsum[i] += __shfl_xor(lsum[i], 16);
      lsum[i] += __shfl_xor(lsum[i], 32);   // lane(q,r) holds sum for row r
    }
#pragma unroll
    for (int i = 0; i < 2; ++i) {
      float inv[4];
#pragma unroll
      for (int g = 0; g < 4; ++g)
        inv[g] = 1.f / __shfl(lsum[i], 4 * q + g);
#pragma unroll
      for (int g = 0; g < 4; ++g) {
        u16* yp = Yb + (size_t)(baseq + 16 * i + 4 * q + g) * DIM + h * 64 + r;
        yp[0]  = f2bf(O[i][0][g] * inv[g]);
        yp[16] = f2bf(O[i][1][g] * inv[g]);
        yp[32] = f2bf(O[i][2][g] * inv[g]);
        yp[48] = f2bf(O[i][3][g] * inv[g]);
      }
    }
  };

  if (w == 0) {
#pragma unroll
    for (int i = 0; i < 2; ++i) {
#pragma unroll
      for (int t = 0; t < 4; ++t)
#pragma unroll
        for (int g = 0; g < 4; ++g)
          OA[i][t][g] += OcA[(i * 4 + t) * 4 + g][lane];
      lsumA[i] += LcA[i][lane];
    }
    finalize(baseqA, OA, lsumA);
  } else {
#pragma unroll
    for (int i = 0; i < 2; ++i) {
#pragma unroll
      for (int t = 0; t < 4; ++t)
#pragma unroll
        for (int g = 0; g < 4; ++g)
          OB[i][t][g] += OcB[(i * 4 + t) * 4 + g][lane];
      lsumB[i] += LcB[i][lane];
    }
    finalize(baseqB, OB, lsumB);
  }
}

// ---------------------------------------------------------------------------
extern "C" void kernel_launch(void* const* d_in, const int* in_sizes, int n_in,
                              void* d_out, int out_size, void* d_ws, size_t ws_size,
                              hipStream_t stream) {
  const float* x  = (const float*)d_in[0];
  const float* Wq = (const float*)d_in[1];
  const float* Wk = (const float*)d_in[2];
  const float* Wv = (const float*)d_in[3];
  const float* Wo = (const float*)d_in[4];
  const float* cs = (const float*)d_in[5];
  const float* sn = (const float*)d_in[6];

  u16* ws  = (u16*)d_ws;
  u16* xb  = ws;                            // order must match cvt_all segments
  u16* Wqb = xb  + (size_t)N_TOK * DIM;
  u16* Wkb = Wqb + (size_t)DIM * DIM;
  u16* Wvb = Wkb + (size_t)KVD * DIM;
  u16* Wob = Wvb + (size_t)KVD * DIM;
  u16* Qp  = Wob + (size_t)DIM * DIM;       // frag-packed Q (8MB)
  u16* Kp  = Qp  + (size_t)N_TOK * DIM;     // frag-packed K (1MB)
  u16* Vp  = Kp  + (size_t)N_TOK * KVD;     // frag-packed V (1MB)
  u16* Yb  = Vp  + (size_t)N_TOK * KVD;

  // fp32 -> bf16 (x + 4 weights); cos/sin consumed as fp32 by gemm_qkv
  cvt_all<<<dim3(13312), 256, 0, stream>>>(x, Wq, Wk, Wv, Wo, ws);

  // Fused QKV projection + RoPE, frag-packed outputs
  gemm_qkv<<<dim3(640), 256, 0, stream>>>(xb, Wqb, Wkb, Wvb, cs, sn, Qp, Kp, Vp);

  // Balanced pair-scheduled attention (every block = exactly 33 key-tiles)
  attn_mfma<<<dim3(32, 32), 128, 0, stream>>>(Qp, Kp, Vp, Yb);

  // Output projection (fp32 straight to d_out)
  gemm_out<<<dim3(512), 256, 0, stream>>>(Yb, Wob, (float*)d_out);
}